// Round 9
// baseline (740.439 us; speedup 1.0000x reference)
//
#include <hip/hip_runtime.h>
#include <math.h>

#define NB   2048
#define DIN  784
#define HN   256
#define NOUT 10
#define OSTR (HN + HN + NOUT)   // 522

// Per-block LDS: 4 batch rows (one wave each). All fp32.
struct Smem {
  float pl [4][HN];    // parent logits (pl1 for layer-0 scan, then pl2)
  float h1o[4][HN];    // h1 old (0/1)
  float h2o[4][HN];    // h2 old
  float h1n[4][HN];    // h1 new
  float uu [4][HN];    // staged uniforms (u1, then u2)
  float tmp[4][HN];    // nl-init redistribution buffer
};

// ---- bitwise replica of numpy's SIMD float32 exp ---------------------------
__device__ __forceinline__ float np_expf(float xf) {
  float q = __fmul_rn(xf, 1.442695040888963f);       // x * NPY_LOG2Ef
  q = __fadd_rn(q, 12582912.0f);                     // 0x1.8p23 round-to-even
  q = __fsub_rn(q, 12582912.0f);
  float x = __builtin_fmaf(q, -6.93145752e-1f, xf);  // Cody-Waite high
  x = __builtin_fmaf(q, -1.42860677e-6f, x);         // Cody-Waite low
  float num = __builtin_fmaf(x, 5.082762527590693718096e-04f,
                                6.757896990527504603057e-03f);
  num = __builtin_fmaf(num, x, 5.114512081637298353406e-02f);
  num = __builtin_fmaf(num, x, 2.473615434895520810817e-01f);
  num = __builtin_fmaf(num, x, 7.257664613233124478488e-01f);
  num = __builtin_fmaf(num, x, 9.999999999980870924916e-01f);
  float den = __builtin_fmaf(x, 2.159509375685829852307e-02f,
                                -2.742335390411667452936e-01f);
  den = __builtin_fmaf(den, x, 1.0f);
  float r = __fdiv_rn(num, den);
  int qi = (int)q;
  return __fmul_rn(r, __int_as_float((qi + 127) << 23));
}

// Table-free fp64 log1p for e in (0,1]:  t = 1+e (exact, e >= 2^-29 guarded).
// a = 1 / 1.25 / 1.75 by t;  t-a exact (Sterbenz);  z = (t-a)/(t+a), z^2<=0.0083;
// ln(1+e) = ln(a) + 2*atanh(z), exact-Taylor Horner through z^15
// (truncation ~2e-18 rel; total rel err ~1e-15 — same class as round 8's, which
// flipped zero decisions). a=1 bin (ln a = 0) avoids cancellation as e->0.
__device__ __forceinline__ float np_log1pf(float ef, double ln125, double ln175) {
  if (ef < 0x1p-29f) return ef;            // CR(log1p(e)) == e (never taken in practice)
  double t = 1.0 + (double)ef;             // exact
  bool sml = (t < 1.0625);
  bool low = (t < 1.5);
  double a    = sml ? 1.0 : (low ? 1.25  : 1.75);
  double ln_a = sml ? 0.0 : (low ? ln125 : ln175);
  double z = (t - a) / (t + a);
  double u = z * z;
  double p =         2.0 / 15.0;
  p = fma(p, u, 2.0 / 13.0);
  p = fma(p, u, 2.0 / 11.0);
  p = fma(p, u, 2.0 /  9.0);
  p = fma(p, u, 2.0 /  7.0);
  p = fma(p, u, 2.0 /  5.0);
  p = fma(p, u, 2.0 /  3.0);
  p = fma(p, u, 2.0);
  return (float)fma(z, p, ln_a);           // ln_a + z * (2 + u*(2/3 + ...))
}

// sigmoid-CE, numpy op order: (max(l,0) - l*label) + log1p(exp(-|l|))
__device__ __forceinline__ float ce32(float l, float label, double ln125, double ln175) {
  float t3 = __fsub_rn(fmaxf(l, 0.0f), __fmul_rn(l, label));
  return __fadd_rn(t3, np_log1pf(np_expf(-fabsf(l)), ln125, ln175));
}

// sigmoid = 1/(1+np.exp(-z)), IEEE divide
__device__ __forceinline__ float sig32(float z) {
  return __fdiv_rn(1.0f, __fadd_rn(1.0f, np_expf(-z)));
}

// numpy pairwise sum over 10 on lanes 0..9 (uniform result)
__device__ __forceinline__ float sum10(float c) {
  float c0 = __shfl(c, 0), c1 = __shfl(c, 1), c2 = __shfl(c, 2), c3 = __shfl(c, 3);
  float c4 = __shfl(c, 4), c5 = __shfl(c, 5), c6 = __shfl(c, 6), c7 = __shfl(c, 7);
  float c8 = __shfl(c, 8), c9 = __shfl(c, 9);
  float t = __fadd_rn(__fadd_rn(__fadd_rn(c0, c1), __fadd_rn(c2, c3)),
                      __fadd_rn(__fadd_rn(c4, c5), __fadd_rn(c6, c7)));
  t = __fadd_rn(t, c8);
  t = __fadd_rn(t, c9);
  return t;
}

// numpy pairwise sum over 256 children distributed 4/lane.
// GATHER-THEN-FOLD: 16 independent shfls materialized first (ds_bpermutes
// pipeline instead of serializing behind each add), then the strict left fold
// (bitwise-identical arithmetic order to rounds 7/8), then the 8-acc combine.
__device__ __forceinline__ float fold256(const float c[4], int idx) {
  float v0  = __shfl(c[0], idx);
  float v1  = __shfl(c[1], idx);
  float v2  = __shfl(c[2], idx);
  float v3  = __shfl(c[3], idx);
  float v4  = __shfl(c[0], idx + 16);
  float v5  = __shfl(c[1], idx + 16);
  float v6  = __shfl(c[2], idx + 16);
  float v7  = __shfl(c[3], idx + 16);
  float v8  = __shfl(c[0], idx + 32);
  float v9  = __shfl(c[1], idx + 32);
  float v10 = __shfl(c[2], idx + 32);
  float v11 = __shfl(c[3], idx + 32);
  float v12 = __shfl(c[0], idx + 48);
  float v13 = __shfl(c[1], idx + 48);
  float v14 = __shfl(c[2], idx + 48);
  float v15 = __shfl(c[3], idx + 48);
  float r = v0;
  r = __fadd_rn(r, v1);  r = __fadd_rn(r, v2);  r = __fadd_rn(r, v3);
  r = __fadd_rn(r, v4);  r = __fadd_rn(r, v5);  r = __fadd_rn(r, v6);
  r = __fadd_rn(r, v7);  r = __fadd_rn(r, v8);  r = __fadd_rn(r, v9);
  r = __fadd_rn(r, v10); r = __fadd_rn(r, v11); r = __fadd_rn(r, v12);
  r = __fadd_rn(r, v13); r = __fadd_rn(r, v14); r = __fadd_rn(r, v15);
  r = __fadd_rn(r, __shfl_xor(r, 1));
  r = __fadd_rn(r, __shfl_xor(r, 2));
  r = __fadd_rn(r, __shfl_xor(r, 4));
  r = __fadd_rn(r, __shfl_xor(r, 8));
  return r;
}

__global__ __launch_bounds__(256) void stoch_mlp(
    const float* __restrict__ x,  const int* __restrict__ h1,
    const int* __restrict__ h2,   const int* __restrict__ y,
    const float* __restrict__ W1, const float* __restrict__ b1,
    const float* __restrict__ W2, const float* __restrict__ b2,
    const float* __restrict__ Wo, const float* __restrict__ bo,
    const float* __restrict__ u1, const float* __restrict__ u2,
    float* __restrict__ out)
{
  __shared__ Smem sm;
  const int t    = threadIdx.x;
  const int lane = t & 63;
  const int wid  = t >> 6;            // wave id == local batch row
  const int b0   = blockIdx.x * 4;
  const int b    = b0 + wid;

  // ln(a) constants — device-computed (ocml fp64 log), wave-uniform registers
  const double ln125 = log(1.25);
  const double ln175 = log(1.75);

  // ---- phase 1: stage states + uniforms; pl1 = x@W1 (BLAS-faithful fp32) --
  for (int j = lane; j < HN; j += 64) {
    sm.h1o[wid][j] = (float)h1[b * HN + j];
    sm.h2o[wid][j] = (float)h2[b * HN + j];
    sm.uu [wid][j] = u1[(size_t)j * NB + b];
  }
  {
    float a0 = 0.0f, a1 = 0.0f, a2 = 0.0f, a3 = 0.0f;   // sequential-k FMA chain
    const float* x0 = x + (size_t)b0 * DIN;
    for (int k = 0; k < DIN; ++k) {
      float wk = W1[k * HN + t];
      a0 = __builtin_fmaf(x0[k],           wk, a0);
      a1 = __builtin_fmaf(x0[DIN   + k],   wk, a1);
      a2 = __builtin_fmaf(x0[2*DIN + k],   wk, a2);
      a3 = __builtin_fmaf(x0[3*DIN + k],   wk, a3);
    }
    sm.pl[0][t] = __fadd_rn(a0, b1[t]);
    sm.pl[1][t] = __fadd_rn(a1, b1[t]);
    sm.pl[2][t] = __fadd_rn(a2, b1[t]);
    sm.pl[3][t] = __fadd_rn(a3, b1[t]);
  }
  __syncthreads();

  // nl-init = h1_old @ W2 + b2: masked fp32 adds == BLAS FMA chain bitwise
  {
    float acc[4] = {0.0f, 0.0f, 0.0f, 0.0f};
    for (int j = 0; j < HN; ++j) {
      if (sm.h1o[wid][j] != 0.0f) {
        float4 wf = *reinterpret_cast<const float4*>(W2 + (size_t)j * HN + 4*lane);
        acc[0] = __fadd_rn(acc[0], wf.x);  acc[1] = __fadd_rn(acc[1], wf.y);
        acc[2] = __fadd_rn(acc[2], wf.z);  acc[3] = __fadd_rn(acc[3], wf.w);
      }
    }
    float4 bv = *reinterpret_cast<const float4*>(b2 + 4*lane);
    sm.tmp[wid][4*lane + 0] = __fadd_rn(acc[0], bv.x);
    sm.tmp[wid][4*lane + 1] = __fadd_rn(acc[1], bv.y);
    sm.tmp[wid][4*lane + 2] = __fadd_rn(acc[2], bv.z);
    sm.tmp[wid][4*lane + 3] = __fadd_rn(acc[3], bv.w);
  }
  __syncthreads();

  // ---- phase 2: layer-0 scan — 4 children per lane ------------------------
  // lane = 16*g + idx; chain idx = (half, jacc); lane owns m = 4g..4g+3:
  // child k(i) = half*128 + (4g+i)*8 + jacc
  const int idx  = lane & 15;
  const int g    = lane >> 4;
  const int half = idx >> 3;
  const int jacc = idx & 7;
  const int kb   = half * 128 + (4 * g) * 8 + jacc;   // + i*8

  float nlv[4], nv[4], wv[4];
  #pragma unroll
  for (int i = 0; i < 4; ++i) {
    int k = kb + i * 8;
    nlv[i] = sm.tmp[wid][k];
    nv[i]  = sm.h2o[wid][k];
    wv[i]  = W2[k];                    // prefetch row 0
  }
  float S_c;                           // carried-state CE sum (wave-uniform)
  {
    float ci[4];
    #pragma unroll
    for (int i = 0; i < 4; ++i) ci[i] = ce32(nlv[i], nv[i], ln125, ln175);
    S_c = fold256(ci, idx);
  }

  {
    float nodeN = sm.h1o[wid][0], uN = sm.uu[wid][0], plN = sm.pl[wid][0];
    for (int j = 0; j < HN; ++j) {
      float node = nodeN, uj = uN, plj = plN;
      bool  nd   = (node != 0.0f);
      float wcur[4];
      #pragma unroll
      for (int i = 0; i < 4; ++i) wcur[i] = wv[i];
      if (j + 1 < HN) {
        nodeN = sm.h1o[wid][j + 1];
        uN    = sm.uu [wid][j + 1];
        plN   = sm.pl [wid][j + 1];
        #pragma unroll
        for (int i = 0; i < 4; ++i) wv[i] = W2[(size_t)(j + 1) * HN + kb + i * 8];
      }
      float one_m = __fsub_rn(1.0f, node);
      float nl0[4], nl1[4], chg[4];
      #pragma unroll
      for (int i = 0; i < 4; ++i) {
        nl0[i] = __fsub_rn(nlv[i], __fmul_rn(node,  wcur[i]));
        nl1[i] = __fadd_rn(nlv[i], __fmul_rn(one_m, wcur[i]));
        chg[i] = ce32(nd ? nl0[i] : nl1[i], nv[i], ln125, ln175);  // fresh side
      }
      float F  = fold256(chg, idx);    // fresh-side CE sum, numpy order
      float S0 = nd ? F : S_c;         // stale side == carried sum bitwise
      float S1 = nd ? S_c : F;
      float z    = __fsub_rn(__fadd_rn(plj, -S1), -S0);   // (pl + lp1) - lp0
      float prob = sig32(z);
      bool  nw   = (uj < prob);
      #pragma unroll
      for (int i = 0; i < 4; ++i) nlv[i] = nw ? nl1[i] : nl0[i];
      S_c = (nw != nd) ? F : S_c;
      if (lane == 0) sm.h1n[wid][j] = nw ? 1.0f : 0.0f;
    }
  }
  __syncthreads();

  // ---- phase 3: pl2 = h1_new @ W2 + b2 (masked fp32 == BLAS chain) --------
  {
    float acc[4] = {0.0f, 0.0f, 0.0f, 0.0f};
    for (int j = 0; j < HN; ++j) {
      if (sm.h1n[wid][j] != 0.0f) {
        float4 wf = *reinterpret_cast<const float4*>(W2 + (size_t)j * HN + 4*lane);
        acc[0] = __fadd_rn(acc[0], wf.x);  acc[1] = __fadd_rn(acc[1], wf.y);
        acc[2] = __fadd_rn(acc[2], wf.z);  acc[3] = __fadd_rn(acc[3], wf.w);
      }
    }
    float4 bv = *reinterpret_cast<const float4*>(b2 + 4*lane);
    sm.pl[wid][4*lane + 0] = __fadd_rn(acc[0], bv.x);
    sm.pl[wid][4*lane + 1] = __fadd_rn(acc[1], bv.y);
    sm.pl[wid][4*lane + 2] = __fadd_rn(acc[2], bv.z);
    sm.pl[wid][4*lane + 3] = __fadd_rn(acc[3], bv.w);
  }
  for (int j = lane; j < HN; j += 64) sm.uu[wid][j] = u2[(size_t)j * NB + b];

  // layer-1 init: nlo = h2_old @ Wout + bout (masked fp32); nvy = y
  float nvy = 0.0f, nlo = 0.0f;
  if (lane < NOUT) {
    nvy = (float)y[b * NOUT + lane];
    float a = 0.0f;
    for (int j = 0; j < HN; ++j)
      if (sm.h2o[wid][j] != 0.0f) a = __fadd_rn(a, Wo[j * NOUT + lane]);
    nlo = __fadd_rn(a, bo[lane]);
  }
  float S_c1 = sum10((lane < NOUT) ? ce32(nlo, nvy, ln125, ln175) : 0.0f);
  __syncthreads();

  // ---- phase 4: layer-1 scan (10 children on lanes 0..9) ------------------
  {
    float wnext = (lane < NOUT) ? Wo[lane] : 0.0f;
    for (int j = 0; j < HN; ++j) {
      float node = sm.h2o[wid][j];
      float uj   = sm.uu[wid][j];
      float plj  = sm.pl[wid][j];
      bool  nd   = (node != 0.0f);
      float w    = wnext;
      if (j + 1 < HN) wnext = (lane < NOUT) ? Wo[(j + 1) * NOUT + lane] : 0.0f;
      float one_m = __fsub_rn(1.0f, node);
      float nl0 = __fsub_rn(nlo, __fmul_rn(node,  w));
      float nl1 = __fadd_rn(nlo, __fmul_rn(one_m, w));
      float chg = (lane < NOUT) ? ce32(nd ? nl0 : nl1, nvy, ln125, ln175) : 0.0f;
      float F   = sum10(chg);
      float S0  = nd ? F : S_c1;
      float S1  = nd ? S_c1 : F;
      float z    = __fsub_rn(__fadd_rn(plj, -S1), -S0);
      float prob = sig32(z);
      bool  nw   = (uj < prob);
      nlo  = nw ? nl1 : nl0;
      S_c1 = (nw != nd) ? F : S_c1;
      if (lane == 0) out[(size_t)b * OSTR + HN + j] = nw ? 1.0f : 0.0f;
    }
  }

  // ---- phase 5: outputs ---------------------------------------------------
  float* orow = out + (size_t)b * OSTR;
  for (int j = lane; j < HN; j += 64) orow[j] = sm.h1n[wid][j];
  if (lane < NOUT) orow[2*HN + lane] = nlo;
}

extern "C" void kernel_launch(void* const* d_in, const int* in_sizes, int n_in,
                              void* d_out, int out_size, void* d_ws, size_t ws_size,
                              hipStream_t stream) {
  const float* x  = (const float*)d_in[0];
  const int*   h1 = (const int*)  d_in[1];
  const int*   h2 = (const int*)  d_in[2];
  const int*   y  = (const int*)  d_in[3];
  const float* W1 = (const float*)d_in[4];
  const float* b1 = (const float*)d_in[5];
  const float* W2 = (const float*)d_in[6];
  const float* b2 = (const float*)d_in[7];
  const float* Wo = (const float*)d_in[8];
  const float* bo = (const float*)d_in[9];
  const float* u1 = (const float*)d_in[10];
  const float* u2 = (const float*)d_in[11];
  stoch_mlp<<<NB/4, 256, 0, stream>>>(x, h1, h2, y, W1, b1, W2, b2, Wo, bo, u1, u2,
                                      (float*)d_out);
}

// Round 10
// 640.221 us; speedup vs baseline: 1.1565x; 1.1565x over previous
//
#include <hip/hip_runtime.h>
#include <math.h>

#define NB   2048
#define DIN  784
#define HN   256
#define NOUT 10
#define OSTR (HN + HN + NOUT)   // 522

// Per-block LDS. sup/tab/scr are 16B-aligned by placement order.
struct Smem {
  float4  sup[4][HN];      // 16 KB: (node, u, parent-logit, 0) per j — packed staging
  double2 tab[17];         // 272 B: {ln(k/16), 16/k}, k=16..32 (device-built)
  float   scr[4][16 * 20]; // 5 KB fold scratch: row idx (16 rows × 20 cols, +4 pad)
  float   h2o[4][HN];      // 4 KB
  float   h1n[4][HN];      // 4 KB
  float   tmp[4][HN];      // 4 KB nl-init redistribution
  float   yv [4][16];
};

// ---- bitwise replica of numpy's SIMD float32 exp ---------------------------
__device__ __forceinline__ float np_expf(float xf) {
  float q = __fmul_rn(xf, 1.442695040888963f);       // x * NPY_LOG2Ef
  q = __fadd_rn(q, 12582912.0f);                     // 0x1.8p23 round-to-even
  q = __fsub_rn(q, 12582912.0f);
  float x = __builtin_fmaf(q, -6.93145752e-1f, xf);  // Cody-Waite high
  x = __builtin_fmaf(q, -1.42860677e-6f, x);         // Cody-Waite low
  float num = __builtin_fmaf(x, 5.082762527590693718096e-04f,
                                6.757896990527504603057e-03f);
  num = __builtin_fmaf(num, x, 5.114512081637298353406e-02f);
  num = __builtin_fmaf(num, x, 2.473615434895520810817e-01f);
  num = __builtin_fmaf(num, x, 7.257664613233124478488e-01f);
  num = __builtin_fmaf(num, x, 9.999999999980870924916e-01f);
  float den = __builtin_fmaf(x, 2.159509375685829852307e-02f,
                                -2.742335390411667452936e-01f);
  den = __builtin_fmaf(den, x, 1.0f);
  float r = __fdiv_rn(num, den);
  int qi = (int)q;
  return __fmul_rn(r, __int_as_float((qi + 127) << 23));
}

// Round-8 table log1p, verbatim arithmetic; tables interleaved -> 1 ds_read_b128.
__device__ __forceinline__ float np_log1pf(float ef, const double2* __restrict__ tab) {
  if (ef < 0x1p-29f) return ef;            // never taken in practice
  double t  = 1.0 + (double)ef;            // exact
  double kd = rint(t * 16.0);              // k in [16, 32]
  int   idx = (int)kd - 16;
  double c  = kd * 0.0625;                 // exact
  double2 te = tab[idx];                   // {ln(c), 16/k} in one load
  double s  = (t - c) * te.y;              // t-c exact (Sterbenz)
  double p  = fma(s, 1.0/9.0, -0.125);
  p = fma(p, s,  1.0/7.0);
  p = fma(p, s, -1.0/6.0);
  p = fma(p, s,  1.0/5.0);
  p = fma(p, s, -0.25);
  p = fma(p, s,  1.0/3.0);
  p = fma(p, s, -0.5);
  p = fma(p, s,  1.0);
  p = p * s;                               // ln(1+s)
  return (float)(te.x + p);
}

// sigmoid-CE, numpy op order: (max(l,0) - l*label) + log1p(exp(-|l|))
__device__ __forceinline__ float ce32(float l, float label, const double2* __restrict__ tab) {
  float t3 = __fsub_rn(fmaxf(l, 0.0f), __fmul_rn(l, label));
  return __fadd_rn(t3, np_log1pf(np_expf(-fabsf(l)), tab));
}

// sigmoid = 1/(1+np.exp(-z)), IEEE divide
__device__ __forceinline__ float sig32(float z) {
  return __fdiv_rn(1.0f, __fadd_rn(1.0f, np_expf(-z)));
}

// lane data movement (bitwise-safe): DPP quad_perm xor1/xor2, ds_swizzle xor4/xor8
template<int CTRL> __device__ __forceinline__ float dppx(float v) {
  return __int_as_float(__builtin_amdgcn_mov_dpp(__float_as_int(v), CTRL, 0xF, 0xF, true));
}
template<int OFFS> __device__ __forceinline__ float swzx(float v) {
  return __int_as_float(__builtin_amdgcn_ds_swizzle(__float_as_int(v), OFFS));
}

// numpy pairwise sum over 10 on lanes 0..9 (uniform result)
__device__ __forceinline__ float sum10(float c) {
  float c0 = __shfl(c, 0), c1 = __shfl(c, 1), c2 = __shfl(c, 2), c3 = __shfl(c, 3);
  float c4 = __shfl(c, 4), c5 = __shfl(c, 5), c6 = __shfl(c, 6), c7 = __shfl(c, 7);
  float c8 = __shfl(c, 8), c9 = __shfl(c, 9);
  float t = __fadd_rn(__fadd_rn(__fadd_rn(c0, c1), __fadd_rn(c2, c3)),
                      __fadd_rn(__fadd_rn(c4, c5), __fadd_rn(c6, c7)));
  t = __fadd_rn(t, c8);
  t = __fadd_rn(t, c9);
  return t;
}

// numpy pairwise sum over 256 children (4/lane) via LDS scratch transpose.
// scrw = &scr[wid][0]. Lane 16g+idx writes its chg[0..3] (chain terms m=4g..4g+3)
// to row idx cols 4g..4g+3, reads back the full 16-term row, strict left fold
// (numpy 8-acc chain order), then xor-tail 1,2,4,8 (== rounds 7-9 bitwise).
__device__ __forceinline__ float fold256_lds(const float c[4], float* __restrict__ scrw,
                                             int idx, int g) {
  *reinterpret_cast<float4*>(scrw + idx * 20 + 4 * g) = make_float4(c[0], c[1], c[2], c[3]);
  const float4* rp = reinterpret_cast<const float4*>(scrw + idx * 20);
  float4 q0 = rp[0], q1 = rp[1], q2 = rp[2], q3 = rp[3];
  float r = q0.x;
  r = __fadd_rn(r, q0.y); r = __fadd_rn(r, q0.z); r = __fadd_rn(r, q0.w);
  r = __fadd_rn(r, q1.x); r = __fadd_rn(r, q1.y); r = __fadd_rn(r, q1.z); r = __fadd_rn(r, q1.w);
  r = __fadd_rn(r, q2.x); r = __fadd_rn(r, q2.y); r = __fadd_rn(r, q2.z); r = __fadd_rn(r, q2.w);
  r = __fadd_rn(r, q3.x); r = __fadd_rn(r, q3.y); r = __fadd_rn(r, q3.z); r = __fadd_rn(r, q3.w);
  r = __fadd_rn(r, dppx<0xB1>(r));      // xor 1 (quad_perm [1,0,3,2])
  r = __fadd_rn(r, dppx<0x4E>(r));      // xor 2 (quad_perm [2,3,0,1])
  r = __fadd_rn(r, swzx<0x101F>(r));    // xor 4
  r = __fadd_rn(r, swzx<0x201F>(r));    // xor 8
  return r;
}

__global__ __launch_bounds__(256) void stoch_mlp(
    const float* __restrict__ x,  const int* __restrict__ h1,
    const int* __restrict__ h2,   const int* __restrict__ y,
    const float* __restrict__ W1, const float* __restrict__ b1,
    const float* __restrict__ W2, const float* __restrict__ b2,
    const float* __restrict__ Wo, const float* __restrict__ bo,
    const float* __restrict__ u1, const float* __restrict__ u2,
    float* __restrict__ out)
{
  __shared__ Smem sm;
  const int t    = threadIdx.x;
  const int lane = t & 63;
  const int wid  = t >> 6;            // wave id == local batch row
  const int b0   = blockIdx.x * 4;
  const int b    = b0 + wid;

  // ---- phase 1: tables, states, pl1 = x@W1 (BLAS fp32) + packed staging ---
  if (t < 17) {
    double c = (double)(t + 16) * 0.0625;
    sm.tab[t] = make_double2(log(c), 16.0 / (double)(t + 16));
  }
  for (int j = lane; j < HN; j += 64) sm.h2o[wid][j] = (float)h2[b * HN + j];
  if (lane < 16) sm.yv[wid][lane] = (lane < NOUT) ? (float)y[b * NOUT + lane] : 0.0f;
  {
    float a0 = 0.0f, a1 = 0.0f, a2 = 0.0f, a3 = 0.0f;   // sequential-k FMA chains
    const float* x0 = x + (size_t)b0 * DIN;
    for (int k = 0; k < DIN; ++k) {
      float wk = W1[k * HN + t];
      a0 = __builtin_fmaf(x0[k],           wk, a0);
      a1 = __builtin_fmaf(x0[DIN   + k],   wk, a1);
      a2 = __builtin_fmaf(x0[2*DIN + k],   wk, a2);
      a3 = __builtin_fmaf(x0[3*DIN + k],   wk, a3);
    }
    float bb = b1[t];
    float4 uv = *reinterpret_cast<const float4*>(u1 + (size_t)t * NB + b0);
    float n0 = (float)h1[(b0 + 0) * HN + t];
    float n1 = (float)h1[(b0 + 1) * HN + t];
    float n2 = (float)h1[(b0 + 2) * HN + t];
    float n3 = (float)h1[(b0 + 3) * HN + t];
    sm.sup[0][t] = make_float4(n0, uv.x, __fadd_rn(a0, bb), 0.0f);
    sm.sup[1][t] = make_float4(n1, uv.y, __fadd_rn(a1, bb), 0.0f);
    sm.sup[2][t] = make_float4(n2, uv.z, __fadd_rn(a2, bb), 0.0f);
    sm.sup[3][t] = make_float4(n3, uv.w, __fadd_rn(a3, bb), 0.0f);
  }
  __syncthreads();   // sup written cross-wave; tab cross-wave

  const double2* tab = sm.tab;
  float* scrw = &sm.scr[wid][0];

  // nl-init = h1_old @ W2 + b2 (masked fp32 == BLAS chain)
  {
    float acc[4] = {0.0f, 0.0f, 0.0f, 0.0f};
    for (int j = 0; j < HN; ++j) {
      if (sm.sup[wid][j].x != 0.0f) {
        float4 wf = *reinterpret_cast<const float4*>(W2 + (size_t)j * HN + 4*lane);
        acc[0] = __fadd_rn(acc[0], wf.x);  acc[1] = __fadd_rn(acc[1], wf.y);
        acc[2] = __fadd_rn(acc[2], wf.z);  acc[3] = __fadd_rn(acc[3], wf.w);
      }
    }
    float4 bv = *reinterpret_cast<const float4*>(b2 + 4*lane);
    *reinterpret_cast<float4*>(&sm.tmp[wid][4*lane]) =
        make_float4(__fadd_rn(acc[0], bv.x), __fadd_rn(acc[1], bv.y),
                    __fadd_rn(acc[2], bv.z), __fadd_rn(acc[3], bv.w));
  }
  // tmp is wave-private; same-wave DS ordering makes it visible without barrier

  // ---- phase 2: layer-0 scan — 4 children per lane ------------------------
  const int idx  = lane & 15;
  const int g    = lane >> 4;
  const int half = idx >> 3;
  const int jacc = idx & 7;
  const int kb   = half * 128 + (4 * g) * 8 + jacc;   // + i*8

  float nlv[4], nv[4], wv[4];
  #pragma unroll
  for (int i = 0; i < 4; ++i) {
    int k = kb + i * 8;
    nlv[i] = sm.tmp[wid][k];
    nv[i]  = sm.h2o[wid][k];
    wv[i]  = W2[k];                    // row 0
  }
  float S_c;                           // carried-state CE sum (wave-uniform)
  {
    float ci[4];
    #pragma unroll
    for (int i = 0; i < 4; ++i) ci[i] = ce32(nlv[i], nv[i], tab);
    S_c = fold256_lds(ci, scrw, idx, g);
  }

  {
    float4 supC = sm.sup[wid][0];
    for (int j = 0; j < HN; ++j) {
      float node = supC.x, uj = supC.y, plj = supC.z;
      bool  nd   = (node != 0.0f);
      int   jn   = (j + 1) & (HN - 1);           // branchless wrapped prefetch
      float4 supN = sm.sup[wid][jn];
      float wcur[4];
      #pragma unroll
      for (int i = 0; i < 4; ++i) wcur[i] = wv[i];
      #pragma unroll
      for (int i = 0; i < 4; ++i) wv[i] = W2[(size_t)jn * HN + kb + i * 8];
      float one_m = __fsub_rn(1.0f, node);
      float nl0[4], nl1[4], chg[4];
      #pragma unroll
      for (int i = 0; i < 4; ++i) {
        nl0[i] = __fsub_rn(nlv[i], __fmul_rn(node,  wcur[i]));
        nl1[i] = __fadd_rn(nlv[i], __fmul_rn(one_m, wcur[i]));
        chg[i] = ce32(nd ? nl0[i] : nl1[i], nv[i], tab);  // fresh side only
      }
      float F  = fold256_lds(chg, scrw, idx, g);  // fresh-side CE sum, numpy order
      float S0 = nd ? F : S_c;                    // stale side == carried sum bitwise
      float S1 = nd ? S_c : F;
      float z    = __fsub_rn(__fadd_rn(plj, -S1), -S0);   // (pl + lp1) - lp0
      float prob = sig32(z);
      bool  nw   = (uj < prob);
      #pragma unroll
      for (int i = 0; i < 4; ++i) nlv[i] = nw ? nl1[i] : nl0[i];
      S_c = (nw != nd) ? F : S_c;
      if (lane == 0) sm.h1n[wid][j] = nw ? 1.0f : 0.0f;
      supC = supN;
    }
  }
  // h1n wave-private; no barrier needed

  // ---- phase 3: pl2 = h1_new @ W2 + b2 (masked fp32); repack staging ------
  {
    float acc[4] = {0.0f, 0.0f, 0.0f, 0.0f};
    for (int j = 0; j < HN; ++j) {
      if (sm.h1n[wid][j] != 0.0f) {
        float4 wf = *reinterpret_cast<const float4*>(W2 + (size_t)j * HN + 4*lane);
        acc[0] = __fadd_rn(acc[0], wf.x);  acc[1] = __fadd_rn(acc[1], wf.y);
        acc[2] = __fadd_rn(acc[2], wf.z);  acc[3] = __fadd_rn(acc[3], wf.w);
      }
    }
    float4 bv = *reinterpret_cast<const float4*>(b2 + 4*lane);
    float p2[4] = {__fadd_rn(acc[0], bv.x), __fadd_rn(acc[1], bv.y),
                   __fadd_rn(acc[2], bv.z), __fadd_rn(acc[3], bv.w)};
    #pragma unroll
    for (int i = 0; i < 4; ++i) {
      int j = 4 * lane + i;
      sm.sup[wid][j] = make_float4(sm.h2o[wid][j], u2[(size_t)j * NB + b], p2[i], 0.0f);
    }
  }

  // layer-1 init: nlo = h2_old @ Wout + bout (masked fp32); nvy = y
  float nvy = 0.0f, nlo = 0.0f;
  if (lane < NOUT) {
    nvy = sm.yv[wid][lane];
    float a = 0.0f;
    for (int j = 0; j < HN; ++j)
      if (sm.h2o[wid][j] != 0.0f) a = __fadd_rn(a, Wo[j * NOUT + lane]);
    nlo = __fadd_rn(a, bo[lane]);
  }
  float S_c1 = sum10((lane < NOUT) ? ce32(nlo, nvy, tab) : 0.0f);

  // ---- phase 4: layer-1 scan (10 children on lanes 0..9) ------------------
  {
    float w = (lane < NOUT) ? Wo[lane] : 0.0f;
    float4 supC = sm.sup[wid][0];
    for (int j = 0; j < HN; ++j) {
      float node = supC.x, uj = supC.y, plj = supC.z;
      bool  nd   = (node != 0.0f);
      int   jn   = (j + 1) & (HN - 1);
      float4 supN = sm.sup[wid][jn];
      float wnn = (lane < NOUT) ? Wo[jn * NOUT + lane] : 0.0f;
      float one_m = __fsub_rn(1.0f, node);
      float nl0 = __fsub_rn(nlo, __fmul_rn(node,  w));
      float nl1 = __fadd_rn(nlo, __fmul_rn(one_m, w));
      float chg = (lane < NOUT) ? ce32(nd ? nl0 : nl1, nvy, tab) : 0.0f;
      float F   = sum10(chg);
      float S0  = nd ? F : S_c1;
      float S1  = nd ? S_c1 : F;
      float z    = __fsub_rn(__fadd_rn(plj, -S1), -S0);
      float prob = sig32(z);
      bool  nw   = (uj < prob);
      nlo  = nw ? nl1 : nl0;
      S_c1 = (nw != nd) ? F : S_c1;
      if (lane == 0) out[(size_t)b * OSTR + HN + j] = nw ? 1.0f : 0.0f;
      supC = supN;
      w = wnn;
    }
  }

  // ---- phase 5: outputs ---------------------------------------------------
  float* orow = out + (size_t)b * OSTR;
  for (int j = lane; j < HN; j += 64) orow[j] = sm.h1n[wid][j];
  if (lane < NOUT) orow[2*HN + lane] = nlo;
}

extern "C" void kernel_launch(void* const* d_in, const int* in_sizes, int n_in,
                              void* d_out, int out_size, void* d_ws, size_t ws_size,
                              hipStream_t stream) {
  const float* x  = (const float*)d_in[0];
  const int*   h1 = (const int*)  d_in[1];
  const int*   h2 = (const int*)  d_in[2];
  const int*   y  = (const int*)  d_in[3];
  const float* W1 = (const float*)d_in[4];
  const float* b1 = (const float*)d_in[5];
  const float* W2 = (const float*)d_in[6];
  const float* b2 = (const float*)d_in[7];
  const float* Wo = (const float*)d_in[8];
  const float* bo = (const float*)d_in[9];
  const float* u1 = (const float*)d_in[10];
  const float* u2 = (const float*)d_in[11];
  stoch_mlp<<<NB/4, 256, 0, stream>>>(x, h1, h2, y, W1, b1, W2, b2, Wo, bo, u1, u2,
                                      (float*)d_out);
}

// Round 11
// 578.376 us; speedup vs baseline: 1.2802x; 1.1069x over previous
//
#include <hip/hip_runtime.h>
#include <math.h>

#define NB   2048
#define DIN  784
#define HN   256
#define NOUT 10
#define OSTR (HN + HN + NOUT)   // 522

// Per-block LDS. sup/tab/scr are 16B-aligned by placement order.
struct Smem {
  float4  sup[4][HN];      // 16 KB: (node, u, parent-logit, 0) per j — packed staging
  double2 tab[65];         // 1040 B: {ln(k/64), 64/k}, k=64..128 (device-built)
  float   scr[4][16 * 20]; // 5 KB fold scratch: row idx (16 rows × 20 cols)
  float   h2o[4][HN];      // 4 KB
  float   h1n[4][HN];      // 4 KB
  float   tmp[4][HN];      // 4 KB nl-init redistribution
  float   yv [4][16];
};

// ---- bitwise replica of numpy's SIMD float32 exp ---------------------------
__device__ __forceinline__ float np_expf(float xf) {
  float q = __fmul_rn(xf, 1.442695040888963f);       // x * NPY_LOG2Ef
  q = __fadd_rn(q, 12582912.0f);                     // 0x1.8p23 round-to-even
  q = __fsub_rn(q, 12582912.0f);
  float x = __builtin_fmaf(q, -6.93145752e-1f, xf);  // Cody-Waite high
  x = __builtin_fmaf(q, -1.42860677e-6f, x);         // Cody-Waite low
  float num = __builtin_fmaf(x, 5.082762527590693718096e-04f,
                                6.757896990527504603057e-03f);
  num = __builtin_fmaf(num, x, 5.114512081637298353406e-02f);
  num = __builtin_fmaf(num, x, 2.473615434895520810817e-01f);
  num = __builtin_fmaf(num, x, 7.257664613233124478488e-01f);
  num = __builtin_fmaf(num, x, 9.999999999980870924916e-01f);
  float den = __builtin_fmaf(x, 2.159509375685829852307e-02f,
                                -2.742335390411667452936e-01f);
  den = __builtin_fmaf(den, x, 1.0f);
  float r = __fdiv_rn(num, den);
  int qi = (int)q;
  return __fmul_rn(r, __int_as_float((qi + 127) << 23));
}

// fp64 log1p for e in (0,1]: t=1+e exact; k=rint(64t) in [64,128]; c=k/64 exact;
// s=(t-c)*(64/k), |s|<=1/128 (t-c exact by Sterbenz); ln(1+s) degree-6 Horner
// (truncation <= ~3e-14 rel — round-8 error class, which flipped zero bits).
__device__ __forceinline__ float np_log1pf(float ef, const double2* __restrict__ tab) {
  if (ef < 0x1p-29f) return ef;            // never taken in practice
  double t  = 1.0 + (double)ef;            // exact
  double kd = rint(t * 64.0);              // k in [64, 128]
  int   idx = (int)kd - 64;
  double2 te = tab[idx];                   // {ln(c), 64/k} in one ds_read_b128
  double c  = kd * 0.015625;               // exact
  double s  = (t - c) * te.y;
  double p  = fma(s, -1.0/6.0, 0.2);       // s(1+s(-1/2+s(1/3+s(-1/4+s(1/5 - s/6)))))
  p = fma(p, s, -0.25);
  p = fma(p, s,  1.0/3.0);
  p = fma(p, s, -0.5);
  p = fma(p, s,  1.0);
  p = p * s;                               // ln(1+s)
  return (float)(te.x + p);
}

// sigmoid-CE, numpy op order: (max(l,0) - l*label) + log1p(exp(-|l|))
__device__ __forceinline__ float ce32(float l, float label, const double2* __restrict__ tab) {
  float t3 = __fsub_rn(fmaxf(l, 0.0f), __fmul_rn(l, label));
  return __fadd_rn(t3, np_log1pf(np_expf(-fabsf(l)), tab));
}

// Decision u < prob where prob = fl(1 / fl(1+exp(-z))) — divide-free:
// sign of d = fma(u,w,-1) decides except within |d|<1e-5 of the boundary
// (slack 5e-6 >> CR div error 1.5e-8); exact replica fallback there (wave-
// uniform condition, ~never taken).
__device__ __forceinline__ bool decide(float u, float ez) {
  float w = __fadd_rn(1.0f, ez);
  float d = __builtin_fmaf(u, w, -1.0f);
  if (__builtin_expect(fabsf(d) < 1e-5f, 0)) {
    float prob = __fdiv_rn(1.0f, w);
    return u < prob;
  }
  return d < 0.0f;
}

// lane data movement (bitwise-safe)
template<int CTRL> __device__ __forceinline__ float dppx(float v) {
  return __int_as_float(__builtin_amdgcn_mov_dpp(__float_as_int(v), CTRL, 0xF, 0xF, true));
}
__device__ __forceinline__ float rdl(float v, int l) {
  return __int_as_float(__builtin_amdgcn_readlane(__float_as_int(v), l));
}

// numpy pairwise sum over 10 on lanes 0..9 (uniform result)
__device__ __forceinline__ float sum10(float c) {
  float c0 = rdl(c, 0), c1 = rdl(c, 1), c2 = rdl(c, 2), c3 = rdl(c, 3);
  float c4 = rdl(c, 4), c5 = rdl(c, 5), c6 = rdl(c, 6), c7 = rdl(c, 7);
  float c8 = rdl(c, 8), c9 = rdl(c, 9);
  float t = __fadd_rn(__fadd_rn(__fadd_rn(c0, c1), __fadd_rn(c2, c3)),
                      __fadd_rn(__fadd_rn(c4, c5), __fadd_rn(c6, c7)));
  t = __fadd_rn(t, c8);
  t = __fadd_rn(t, c9);
  return t;
}

// numpy pairwise sum over 256 children (4/lane) via LDS scratch transpose.
// Lane 16g+idx writes chain idx terms m=4g..4g+3; reads full 16-term row;
// strict left fold; DPP xor1/xor2 give quad sums B0..B3 on lanes 0/4/8/12;
// readlane tail computes (B0+B1)+(B2+B3) — bitwise == the old xor4/xor8.
__device__ __forceinline__ float fold256_lds(const float c[4], float* __restrict__ scrw,
                                             int idx, int g) {
  *reinterpret_cast<float4*>(scrw + idx * 20 + 4 * g) = make_float4(c[0], c[1], c[2], c[3]);
  const float4* rp = reinterpret_cast<const float4*>(scrw + idx * 20);
  float4 q0 = rp[0], q1 = rp[1], q2 = rp[2], q3 = rp[3];
  float r = q0.x;
  r = __fadd_rn(r, q0.y); r = __fadd_rn(r, q0.z); r = __fadd_rn(r, q0.w);
  r = __fadd_rn(r, q1.x); r = __fadd_rn(r, q1.y); r = __fadd_rn(r, q1.z); r = __fadd_rn(r, q1.w);
  r = __fadd_rn(r, q2.x); r = __fadd_rn(r, q2.y); r = __fadd_rn(r, q2.z); r = __fadd_rn(r, q2.w);
  r = __fadd_rn(r, q3.x); r = __fadd_rn(r, q3.y); r = __fadd_rn(r, q3.z); r = __fadd_rn(r, q3.w);
  r = __fadd_rn(r, dppx<0xB1>(r));      // xor 1 (quad_perm [1,0,3,2])
  r = __fadd_rn(r, dppx<0x4E>(r));      // xor 2 (quad_perm [2,3,0,1])
  float B0 = rdl(r, 0), B1 = rdl(r, 4), B2 = rdl(r, 8), B3 = rdl(r, 12);
  return __fadd_rn(__fadd_rn(B0, B1), __fadd_rn(B2, B3));
}

__global__ __launch_bounds__(256) void stoch_mlp(
    const float* __restrict__ x,  const int* __restrict__ h1,
    const int* __restrict__ h2,   const int* __restrict__ y,
    const float* __restrict__ W1, const float* __restrict__ b1,
    const float* __restrict__ W2, const float* __restrict__ b2,
    const float* __restrict__ Wo, const float* __restrict__ bo,
    const float* __restrict__ u1, const float* __restrict__ u2,
    float* __restrict__ out)
{
  __shared__ Smem sm;
  const int t    = threadIdx.x;
  const int lane = t & 63;
  const int wid  = t >> 6;            // wave id == local batch row
  const int b0   = blockIdx.x * 4;
  const int b    = b0 + wid;

  // ---- phase 1: tables, states, pl1 = x@W1 (BLAS fp32) + packed staging ---
  if (t < 65) {
    double c = (double)(t + 64) * 0.015625;
    sm.tab[t] = make_double2(log(c), 64.0 / (double)(t + 64));
  }
  for (int j = lane; j < HN; j += 64) sm.h2o[wid][j] = (float)h2[b * HN + j];
  if (lane < 16) sm.yv[wid][lane] = (lane < NOUT) ? (float)y[b * NOUT + lane] : 0.0f;
  {
    float a0 = 0.0f, a1 = 0.0f, a2 = 0.0f, a3 = 0.0f;   // sequential-k FMA chains
    const float* x0 = x + (size_t)b0 * DIN;
    for (int k = 0; k < DIN; ++k) {
      float wk = W1[k * HN + t];
      a0 = __builtin_fmaf(x0[k],           wk, a0);
      a1 = __builtin_fmaf(x0[DIN   + k],   wk, a1);
      a2 = __builtin_fmaf(x0[2*DIN + k],   wk, a2);
      a3 = __builtin_fmaf(x0[3*DIN + k],   wk, a3);
    }
    float bb = b1[t];
    float4 uv = *reinterpret_cast<const float4*>(u1 + (size_t)t * NB + b0);
    float n0 = (float)h1[(b0 + 0) * HN + t];
    float n1 = (float)h1[(b0 + 1) * HN + t];
    float n2 = (float)h1[(b0 + 2) * HN + t];
    float n3 = (float)h1[(b0 + 3) * HN + t];
    sm.sup[0][t] = make_float4(n0, uv.x, __fadd_rn(a0, bb), 0.0f);
    sm.sup[1][t] = make_float4(n1, uv.y, __fadd_rn(a1, bb), 0.0f);
    sm.sup[2][t] = make_float4(n2, uv.z, __fadd_rn(a2, bb), 0.0f);
    sm.sup[3][t] = make_float4(n3, uv.w, __fadd_rn(a3, bb), 0.0f);
  }
  __syncthreads();   // sup + tab written cross-wave

  const double2* tab = sm.tab;
  float* scrw = &sm.scr[wid][0];

  // nl-init = h1_old @ W2 + b2 (masked fp32 == BLAS chain)
  {
    float acc[4] = {0.0f, 0.0f, 0.0f, 0.0f};
    for (int j = 0; j < HN; ++j) {
      if (sm.sup[wid][j].x != 0.0f) {
        float4 wf = *reinterpret_cast<const float4*>(W2 + (size_t)j * HN + 4*lane);
        acc[0] = __fadd_rn(acc[0], wf.x);  acc[1] = __fadd_rn(acc[1], wf.y);
        acc[2] = __fadd_rn(acc[2], wf.z);  acc[3] = __fadd_rn(acc[3], wf.w);
      }
    }
    float4 bv = *reinterpret_cast<const float4*>(b2 + 4*lane);
    *reinterpret_cast<float4*>(&sm.tmp[wid][4*lane]) =
        make_float4(__fadd_rn(acc[0], bv.x), __fadd_rn(acc[1], bv.y),
                    __fadd_rn(acc[2], bv.z), __fadd_rn(acc[3], bv.w));
  }
  // tmp is wave-private; same-wave DS ordering -> no barrier

  // ---- phase 2: layer-0 scan — 4 children per lane ------------------------
  const int idx  = lane & 15;
  const int g    = lane >> 4;
  const int half = idx >> 3;
  const int jacc = idx & 7;
  const int kb   = half * 128 + (4 * g) * 8 + jacc;   // + i*8

  float nlv[4], nv[4], wv[4];
  #pragma unroll
  for (int i = 0; i < 4; ++i) {
    int k = kb + i * 8;
    nlv[i] = sm.tmp[wid][k];
    nv[i]  = sm.h2o[wid][k];
    wv[i]  = W2[k];                    // row 0
  }
  float S_c;                           // carried-state CE sum (wave-uniform)
  {
    float ci[4];
    #pragma unroll
    for (int i = 0; i < 4; ++i) ci[i] = ce32(nlv[i], nv[i], tab);
    S_c = fold256_lds(ci, scrw, idx, g);
  }

  {
    float4 supC = sm.sup[wid][0];
    for (int j = 0; j < HN; ++j) {
      float node = supC.x, uj = supC.y, plj = supC.z;
      bool  nd   = (node != 0.0f);
      int   jn   = (j + 1) & (HN - 1);           // branchless wrapped prefetch
      float4 supN = sm.sup[wid][jn];
      float wcur[4];
      #pragma unroll
      for (int i = 0; i < 4; ++i) wcur[i] = wv[i];
      #pragma unroll
      for (int i = 0; i < 4; ++i) wv[i] = W2[(size_t)jn * HN + kb + i * 8];
      float one_m = __fsub_rn(1.0f, node);
      float nl0[4], nl1[4], chg[4];
      #pragma unroll
      for (int i = 0; i < 4; ++i) {
        nl0[i] = __fsub_rn(nlv[i], __fmul_rn(node,  wcur[i]));
        nl1[i] = __fadd_rn(nlv[i], __fmul_rn(one_m, wcur[i]));
        chg[i] = ce32(nd ? nl0[i] : nl1[i], nv[i], tab);  // fresh side only
      }
      float F  = fold256_lds(chg, scrw, idx, g);  // fresh-side CE sum, numpy order
      float S0 = nd ? F : S_c;                    // stale side == carried sum bitwise
      float S1 = nd ? S_c : F;
      float z    = __fsub_rn(__fadd_rn(plj, -S1), -S0);   // (pl + lp1) - lp0
      bool  nw   = decide(uj, np_expf(-z));
      #pragma unroll
      for (int i = 0; i < 4; ++i) nlv[i] = nw ? nl1[i] : nl0[i];
      S_c = (nw != nd) ? F : S_c;
      if (lane == 0) sm.h1n[wid][j] = nw ? 1.0f : 0.0f;
      supC = supN;
    }
  }
  // h1n wave-private; no barrier needed

  // ---- phase 3: pl2 = h1_new @ W2 + b2 (masked fp32); repack staging ------
  {
    float acc[4] = {0.0f, 0.0f, 0.0f, 0.0f};
    for (int j = 0; j < HN; ++j) {
      if (sm.h1n[wid][j] != 0.0f) {
        float4 wf = *reinterpret_cast<const float4*>(W2 + (size_t)j * HN + 4*lane);
        acc[0] = __fadd_rn(acc[0], wf.x);  acc[1] = __fadd_rn(acc[1], wf.y);
        acc[2] = __fadd_rn(acc[2], wf.z);  acc[3] = __fadd_rn(acc[3], wf.w);
      }
    }
    float4 bv = *reinterpret_cast<const float4*>(b2 + 4*lane);
    float p2[4] = {__fadd_rn(acc[0], bv.x), __fadd_rn(acc[1], bv.y),
                   __fadd_rn(acc[2], bv.z), __fadd_rn(acc[3], bv.w)};
    #pragma unroll
    for (int i = 0; i < 4; ++i) {
      int j = 4 * lane + i;
      sm.sup[wid][j] = make_float4(sm.h2o[wid][j], u2[(size_t)j * NB + b], p2[i], 0.0f);
    }
  }

  // layer-1 init: nlo = h2_old @ Wout + bout (masked fp32); nvy = y
  float nvy = 0.0f, nlo = 0.0f;
  if (lane < NOUT) {
    nvy = sm.yv[wid][lane];
    float a = 0.0f;
    for (int j = 0; j < HN; ++j)
      if (sm.h2o[wid][j] != 0.0f) a = __fadd_rn(a, Wo[j * NOUT + lane]);
    nlo = __fadd_rn(a, bo[lane]);
  }
  float S_c1 = sum10((lane < NOUT) ? ce32(nlo, nvy, tab) : 0.0f);

  // ---- phase 4: layer-1 scan (10 children on lanes 0..9) ------------------
  {
    float w = (lane < NOUT) ? Wo[lane] : 0.0f;
    float4 supC = sm.sup[wid][0];
    for (int j = 0; j < HN; ++j) {
      float node = supC.x, uj = supC.y, plj = supC.z;
      bool  nd   = (node != 0.0f);
      int   jn   = (j + 1) & (HN - 1);
      float4 supN = sm.sup[wid][jn];
      float wnn = (lane < NOUT) ? Wo[jn * NOUT + lane] : 0.0f;
      float one_m = __fsub_rn(1.0f, node);
      float nl0 = __fsub_rn(nlo, __fmul_rn(node,  w));
      float nl1 = __fadd_rn(nlo, __fmul_rn(one_m, w));
      float chg = (lane < NOUT) ? ce32(nd ? nl0 : nl1, nvy, tab) : 0.0f;
      float F   = sum10(chg);
      float S0  = nd ? F : S_c1;
      float S1  = nd ? S_c1 : F;
      float z    = __fsub_rn(__fadd_rn(plj, -S1), -S0);
      bool  nw   = decide(uj, np_expf(-z));
      nlo  = nw ? nl1 : nl0;
      S_c1 = (nw != nd) ? F : S_c1;
      if (lane == 0) out[(size_t)b * OSTR + HN + j] = nw ? 1.0f : 0.0f;
      supC = supN;
      w = wnn;
    }
  }

  // ---- phase 5: outputs ---------------------------------------------------
  float* orow = out + (size_t)b * OSTR;
  for (int j = lane; j < HN; j += 64) orow[j] = sm.h1n[wid][j];
  if (lane < NOUT) orow[2*HN + lane] = nlo;
}

extern "C" void kernel_launch(void* const* d_in, const int* in_sizes, int n_in,
                              void* d_out, int out_size, void* d_ws, size_t ws_size,
                              hipStream_t stream) {
  const float* x  = (const float*)d_in[0];
  const int*   h1 = (const int*)  d_in[1];
  const int*   h2 = (const int*)  d_in[2];
  const int*   y  = (const int*)  d_in[3];
  const float* W1 = (const float*)d_in[4];
  const float* b1 = (const float*)d_in[5];
  const float* W2 = (const float*)d_in[6];
  const float* b2 = (const float*)d_in[7];
  const float* Wo = (const float*)d_in[8];
  const float* bo = (const float*)d_in[9];
  const float* u1 = (const float*)d_in[10];
  const float* u2 = (const float*)d_in[11];
  stoch_mlp<<<NB/4, 256, 0, stream>>>(x, h1, h2, y, W1, b1, W2, b2, Wo, bo, u1, u2,
                                      (float*)d_out);
}